// Round 16
// baseline (348.254 us; speedup 1.0000x reference)
//
#include <hip/hip_runtime.h>
#include <hip/hip_cooperative_groups.h>
#include <math.h>

namespace cg = cooperative_groups;

// Problem constants
#define TT 4096
#define DD 512
#define RR 32
#define CC 32
#define RC 1024
#define LL 2
#define CHUNK 32
#define NCHUNK 128
#define NEG_SLOPE 0.01f
#define LN_EPS 1e-5f

typedef __attribute__((ext_vector_type(8))) __bf16 bf16x8;
typedef __attribute__((ext_vector_type(4))) float f32x4;

__device__ __forceinline__ unsigned short f2bf(float f) {
    unsigned int u = __builtin_bit_cast(unsigned int, f);
    u += 0x7fffu + ((u >> 16) & 1u);   // round-to-nearest-even
    return (unsigned short)(u >> 16);
}
__device__ __forceinline__ float bf2f(unsigned short s) {
    unsigned int u = (unsigned int)s << 16;
    return __builtin_bit_cast(float, u);
}

// ---------------------------------------------------------------------------
// Fused setup: f32->bf16 for x, W0, W1; Wt/Wc pack into Wtc[L,64,512];
// gamma table ggt[L][1024] = e^{-|a_r|} * (cos b_c, sin b_c).
#define NX4  524288   // 4096*512/4
#define NW04 524288   // 2*512*2048/4
#define NW14 131072   // 2*512*512/4
#define NCV  (NX4 + NW04 + NW14)
#define NPK  16384    // 2*64*512/4
#define NGG  2048     // 2*1024
__global__ __launch_bounds__(256) void setup_kernel(const float4* __restrict__ x,
                                                    const float4* __restrict__ W0,
                                                    const float4* __restrict__ W1,
                                                    const float* __restrict__ Wt,
                                                    const float* __restrict__ Wc,
                                                    const float* __restrict__ a,
                                                    const float* __restrict__ b,
                                                    ushort4* __restrict__ xb,
                                                    ushort4* __restrict__ W0b,
                                                    ushort4* __restrict__ W1b,
                                                    ushort4* __restrict__ Wtc,
                                                    float2* __restrict__ ggt) {
    int i = blockIdx.x * 256 + threadIdx.x;
    float4 v;
    ushort4* dst;
    int j;
    if (i < NCV) {
        const float4* src;
        if (i < NX4) { src = x; dst = xb; j = i; }
        else if (i < NX4 + NW04) { src = W0; dst = W0b; j = i - NX4; }
        else { src = W1; dst = W1b; j = i - NX4 - NW04; }
        v = src[j];
    } else {
        int ii = i - NCV;
        if (ii < NPK) {
            int e = ii * 4;
            int l = e >> 15;
            int r = (e >> 9) & 63;
            int k = e & 511;
            v = (r < 32) ? *(const float4*)&Wt[((size_t)l * 32 + r) * 512 + k]
                         : *(const float4*)&Wc[((size_t)l * 32 + (r - 32)) * 512 + k];
            dst = Wtc; j = ii;
        } else {
            int ii2 = ii - NPK;
            if (ii2 >= NGG) return;
            int l = ii2 >> 10;
            int rc = ii2 & 1023;
            int r = rc >> 5, c = rc & 31;
            float e = expf(-fabsf(a[l * RR + r]));
            ggt[ii2] = make_float2(e * cosf(b[l * CC + c]), e * sinf(b[l * CC + c]));
            return;
        }
    }
    ushort4 o;
    o.x = f2bf(v.x); o.y = f2bf(v.y); o.z = f2bf(v.z); o.w = f2bf(v.w);
    dst[j] = o;
}

// ---------------------------------------------------------------------------
// proj + denom fused (R14 champion): tcabs[t,r]=|tr_r|*invd; tcabs[t,32+c]=|ct_c|.
// Tile 64x64, BK=64, 4 waves; named-scalar staging; grid 64.
__global__ __launch_bounds__(256) void proj_denom_kernel(const unsigned short* __restrict__ A,
                                                         const unsigned short* __restrict__ B,
                                                         float* __restrict__ tcabs) {
    __shared__ __align__(16) unsigned short As[64 * 64];
    __shared__ __align__(16) unsigned short Bs[64 * 64];
    const int tid = threadIdx.x;
    const int w = tid >> 6, lane = tid & 63;
    const int bm = blockIdx.x * 64;
    const int K = 512;
    const int srow = tid >> 3;               // 0..31
    const int k8 = tid & 7;
    const int swz = (k8 ^ (srow & 7)) * 8;
    const unsigned short* gA = A + (size_t)(bm + srow) * K + k8 * 8;
    const unsigned short* gB = B + (size_t)srow * K + k8 * 8;
    const int wb = srow * 64 + swz;
    const int fr = lane & 15, hi = lane >> 4;
    f32x4 acc0 = {}, acc1 = {}, acc2 = {}, acc3 = {};

    uint4 va0 = *(const uint4*)gA;
    uint4 va1 = *(const uint4*)(gA + (size_t)32 * K);
    uint4 vb0 = *(const uint4*)gB;
    uint4 vb1 = *(const uint4*)(gB + (size_t)32 * K);
    for (int k0 = 0; k0 < K; k0 += 64) {
        __syncthreads();
        *(uint4*)&As[wb]        = va0;
        *(uint4*)&As[wb + 2048] = va1;
        *(uint4*)&Bs[wb]        = vb0;
        *(uint4*)&Bs[wb + 2048] = vb1;
        __syncthreads();
        if (k0 + 64 < K) {
            va0 = *(const uint4*)(gA + k0 + 64);
            va1 = *(const uint4*)(gA + (size_t)32 * K + k0 + 64);
            vb0 = *(const uint4*)(gB + k0 + 64);
            vb1 = *(const uint4*)(gB + (size_t)32 * K + k0 + 64);
        }
        const int arow = w * 16 + fr;
#pragma unroll
        for (int kk = 0; kk < 2; ++kk) {
            const int ks = kk * 4 + hi;      // 0..7
            bf16x8 af = *(const bf16x8*)&As[arow * 64 + ((ks ^ (arow & 7)) * 8)];
            bf16x8 b0 = *(const bf16x8*)&Bs[(0 * 16 + fr) * 64 + ((ks ^ (fr & 7)) * 8)];
            bf16x8 b1 = *(const bf16x8*)&Bs[(1 * 16 + fr) * 64 + ((ks ^ (fr & 7)) * 8)];
            bf16x8 b2 = *(const bf16x8*)&Bs[(2 * 16 + fr) * 64 + ((ks ^ (fr & 7)) * 8)];
            bf16x8 b3 = *(const bf16x8*)&Bs[(3 * 16 + fr) * 64 + ((ks ^ (fr & 7)) * 8)];
            acc0 = __builtin_amdgcn_mfma_f32_16x16x32_bf16(af, b0, acc0, 0, 0, 0);
            acc1 = __builtin_amdgcn_mfma_f32_16x16x32_bf16(af, b1, acc1, 0, 0, 0);
            acc2 = __builtin_amdgcn_mfma_f32_16x16x32_bf16(af, b2, acc2, 0, 0, 0);
            acc3 = __builtin_amdgcn_mfma_f32_16x16x32_bf16(af, b3, acc3, 0, 0, 0);
        }
    }
#pragma unroll
    for (int q = 0; q < 4; ++q) {
        float a0 = fabsf(acc0[q]), a1 = fabsf(acc1[q]);
        float a2 = fabsf(acc2[q]), a3 = fabsf(acc3[q]);
        float st = a0 + a1, sc = a2 + a3;
        st += __shfl_xor(st, 1); sc += __shfl_xor(sc, 1);
        st += __shfl_xor(st, 2); sc += __shfl_xor(sc, 2);
        st += __shfl_xor(st, 4); sc += __shfl_xor(sc, 4);
        st += __shfl_xor(st, 8); sc += __shfl_xor(sc, 8);
        float inv = 1.f / (1e-8f + st * sc);
        size_t rb = (size_t)(bm + w * 16 + hi * 4 + q) * 64;
        tcabs[rb + fr]      = a0 * inv;
        tcabs[rb + fr + 16] = a1 * inv;
        tcabs[rb + fr + 32] = a2;
        tcabs[rb + fr + 48] = a3;
    }
}

// ---------------------------------------------------------------------------
// Cooperative fused scan: phase 1 = per-(chunk,rc) affine transform (pass1),
// grid-wide sync, phase 2 = lookback + rescan + feature emit (pass2f).
// grid 512 x 256 (all blocks co-resident: ~60 VGPR, 0 LDS).
__global__ __launch_bounds__(256) void scan_fused(const float* __restrict__ tcabs,
                                                  float4* __restrict__ ab4,
                                                  const int* __restrict__ start,
                                                  const float2* __restrict__ ggt,
                                                  const float* __restrict__ s0r,
                                                  const float* __restrict__ s0i,
                                                  unsigned short* __restrict__ scaled) {
    const int bx = blockIdx.x, tx = threadIdx.x;
    // ---- phase 1 (pass1 mapping: tid -> (chunk, rc)) ----
    {
        int tid = bx * 256 + tx;             // 0..131071
        int rc = tid & (RC - 1);
        int chunk = tid >> 10;
        float2 gg = ggt[rc];
        float gr = gg.x, gi = gg.y;
        int r = rc >> 5, c = rc & 31;
        float alr = 1.f, ali = 0.f, ber = 0.f, bei = 0.f;
        int t0 = chunk * CHUNK;
        for (int j = 0; j < CHUNK; ++j) {
            int t = t0 + j;
            float pre = tcabs[t * 64 + r] * tcabs[t * 64 + 32 + c];
            if (start[t]) {
                alr = 0.f; ali = 0.f; ber = pre; bei = 0.f;
            } else {
                float nbr = pre + gr * ber - gi * bei;
                float nbi =       gr * bei + gi * ber;
                float nar = gr * alr - gi * ali;
                float nai = gr * ali + gi * alr;
                ber = nbr; bei = nbi; alr = nar; ali = nai;
            }
        }
        ab4[chunk * RC + rc] = make_float4(alr, ali, ber, bei);
    }
    __threadfence();                          // device-scope: cross-XCD visibility
    cg::this_grid().sync();
    // ---- phase 2 (pass2f mapping, load-balanced chunk remap) ----
    {
        int cid = bx >> 2;
        int chunk = (cid & 1) ? (NCHUNK - 1 - (cid >> 1)) : (cid >> 1);
        int rc = (bx & 3) * 256 + tx;
        float2 gg = ggt[rc];
        float gr = gg.x, gi = gg.y;
        int r = rc >> 5, c = rc & 31;
        float sr = s0r[rc], si = s0i[rc];
        int j = 0;
        for (; j + 8 <= chunk; j += 8) {
            float4 buf[8];
#pragma unroll
            for (int u = 0; u < 8; ++u) buf[u] = ab4[(j + u) * RC + rc];
#pragma unroll
            for (int u = 0; u < 8; ++u) {
                float nsr = buf[u].z + buf[u].x * sr - buf[u].y * si;
                float nsi = buf[u].w + buf[u].x * si + buf[u].y * sr;
                sr = nsr; si = nsi;
            }
        }
        for (; j < chunk; ++j) {
            float4 ab = ab4[j * RC + rc];
            float nsr = ab.z + ab.x * sr - ab.y * si;
            float nsi = ab.w + ab.x * si + ab.y * sr;
            sr = nsr; si = nsi;
        }
        int t0 = chunk * CHUNK;
        for (int jj = 0; jj < CHUNK; ++jj) {
            int t = t0 + jj;
            float pre = tcabs[t * 64 + r] * tcabs[t * 64 + 32 + c];
            if (start[t]) {
                sr = pre; si = 0.f;
            } else {
                float nsr = pre + gr * sr - gi * si;
                float nsi =       gr * si + gi * sr;
                sr = nsr; si = nsi;
            }
            float m2 = sr * sr + si * si;
            float rsq = rsqrtf(m2);
            float m = m2 * rsq;
            float f = (m2 > 0.f) ? log1pf(m) * rsq : 0.f;
            scaled[(size_t)t * 2048 + rc]        = f2bf(si * f);
            scaled[(size_t)t * 2048 + 1024 + rc] = f2bf(sr * f);
        }
    }
}

// ---------------------------------------------------------------------------
// Cm_partial[z][4096,N] = A[4096,Kz]bf16 @ B[N,Kz]bf16^T, stored as BF16.
// Tile 128x64, BK=64, 4 waves, named-scalar staging (R13/R14 champion).
template <int K, int N, int SPLITK>
__global__ __launch_bounds__(256) void gemm_bt_mfma(const unsigned short* __restrict__ A,
                                                    const unsigned short* __restrict__ B,
                                                    unsigned short* __restrict__ Cm) {
    __shared__ __align__(16) unsigned short As[128 * 64];
    __shared__ __align__(16) unsigned short Bs[64 * 64];
    const int tid = threadIdx.x;
    const int w = tid >> 6, lane = tid & 63;
    const int nwg = gridDim.x * gridDim.y * gridDim.z;
    const int id = blockIdx.x + gridDim.x * (blockIdx.y + gridDim.y * blockIdx.z);
    const int lid = (id & 7) * (nwg >> 3) + (id >> 3);
    const int bxs = lid % gridDim.x;
    const int t2 = lid / gridDim.x;
    const int bys = t2 % gridDim.y;
    const int bzs = t2 / gridDim.y;
    const int bm = bys * 128, bn = bxs * 64;
    const int kbeg = bzs * (K / SPLITK);
    const int kend = kbeg + (K / SPLITK);
    const int wr = w >> 1, wc = w & 1;
    const int srow = tid >> 3;               // 0..31
    const int k8 = tid & 7;
    const int swz = (k8 ^ (srow & 7)) * 8;
    const unsigned short* gA = A + (size_t)(bm + srow) * K + k8 * 8;
    const unsigned short* gB = B + (size_t)(bn + srow) * K + k8 * 8;
    const int wAb = srow * 64 + swz;
    const int fr = lane & 15, hi = lane >> 4;
    f32x4 acc[4][2] = {};

    uint4 va0 = *(const uint4*)(gA + kbeg);
    uint4 va1 = *(const uint4*)(gA + (size_t)32 * K + kbeg);
    uint4 va2 = *(const uint4*)(gA + (size_t)64 * K + kbeg);
    uint4 va3 = *(const uint4*)(gA + (size_t)96 * K + kbeg);
    uint4 vb0 = *(const uint4*)(gB + kbeg);
    uint4 vb1 = *(const uint4*)(gB + (size_t)32 * K + kbeg);
    for (int k0 = kbeg; k0 < kend; k0 += 64) {
        __syncthreads();
        *(uint4*)&As[wAb]        = va0;
        *(uint4*)&As[wAb + 2048] = va1;
        *(uint4*)&As[wAb + 4096] = va2;
        *(uint4*)&As[wAb + 6144] = va3;
        *(uint4*)&Bs[wAb]        = vb0;
        *(uint4*)&Bs[wAb + 2048] = vb1;
        __syncthreads();
        if (k0 + 64 < kend) {
            va0 = *(const uint4*)(gA + k0 + 64);
            va1 = *(const uint4*)(gA + (size_t)32 * K + k0 + 64);
            va2 = *(const uint4*)(gA + (size_t)64 * K + k0 + 64);
            va3 = *(const uint4*)(gA + (size_t)96 * K + k0 + 64);
            vb0 = *(const uint4*)(gB + k0 + 64);
            vb1 = *(const uint4*)(gB + (size_t)32 * K + k0 + 64);
        }
#pragma unroll
        for (int kk = 0; kk < 2; ++kk) {
            const int ks = kk * 4 + hi;      // 0..7
            bf16x8 af[4], bfv[2];
#pragma unroll
            for (int mi = 0; mi < 4; ++mi) {
                int row = wr * 64 + mi * 16 + fr;
                af[mi] = *(const bf16x8*)&As[row * 64 + ((ks ^ (row & 7)) * 8)];
            }
#pragma unroll
            for (int ni = 0; ni < 2; ++ni) {
                int row = wc * 32 + ni * 16 + fr;
                bfv[ni] = *(const bf16x8*)&Bs[row * 64 + ((ks ^ (row & 7)) * 8)];
            }
#pragma unroll
            for (int mi = 0; mi < 4; ++mi)
#pragma unroll
                for (int ni = 0; ni < 2; ++ni)
                    acc[mi][ni] = __builtin_amdgcn_mfma_f32_16x16x32_bf16(
                        af[mi], bfv[ni], acc[mi][ni], 0, 0, 0);
        }
    }
    // epilogue: C/D layout col=lane&15, row=(lane>>4)*4+reg  [m89]
    unsigned short* Cz = Cm + (size_t)bzs * TT * N;
    const int ccol0 = bn + wc * 32 + fr;
    const int crow0 = bm + wr * 64 + hi * 4;
#pragma unroll
    for (int ni = 0; ni < 2; ++ni) {
        int col = ccol0 + ni * 16;
#pragma unroll
        for (int mi = 0; mi < 4; ++mi)
#pragma unroll
            for (int q = 0; q < 4; ++q)
                Cz[(size_t)(crow0 + mi * 16 + q) * N + col] = f2bf(acc[mi][ni][q]);
    }
}

// ---------------------------------------------------------------------------
// Wave-per-row LayerNorm + LeakyReLU: y = sum of NP bf16 partials + bias.
template <int NP>
__global__ __launch_bounds__(256) void ln_lrelu_kernel(const unsigned short* __restrict__ yb,
                                                       const float* __restrict__ badd,
                                                       const float* __restrict__ g,
                                                       const float* __restrict__ be,
                                                       unsigned short* __restrict__ zb,
                                                       const float* __restrict__ res,
                                                       unsigned short* __restrict__ hbf,
                                                       float* __restrict__ fout) {
    const int lane = threadIdx.x & 63;
    const int row = blockIdx.x * 4 + (threadIdx.x >> 6);
    const size_t base = (size_t)row * 512 + lane * 8;
    const size_t PS = (size_t)TT * 512;
    const int cb = lane * 8;
    float4 ba = *(const float4*)&badd[cb];
    float4 bb = *(const float4*)&badd[cb + 4];
    float v[8] = {ba.x, ba.y, ba.z, ba.w, bb.x, bb.y, bb.z, bb.w};
#pragma unroll
    for (int zp = 0; zp < NP; ++zp) {
        ushort4 u0 = *(const ushort4*)&yb[zp * PS + base];
        ushort4 u1 = *(const ushort4*)&yb[zp * PS + base + 4];
        v[0] += bf2f(u0.x); v[1] += bf2f(u0.y); v[2] += bf2f(u0.z); v[3] += bf2f(u0.w);
        v[4] += bf2f(u1.x); v[5] += bf2f(u1.y); v[6] += bf2f(u1.z); v[7] += bf2f(u1.w);
    }
    float s = 0.f, ss = 0.f;
#pragma unroll
    for (int j = 0; j < 8; ++j) { s += v[j]; ss += v[j] * v[j]; }
#pragma unroll
    for (int o = 1; o < 64; o <<= 1) {
        s  += __shfl_xor(s, o);
        ss += __shfl_xor(ss, o);
    }
    float m = s * (1.f / 512.f);
    float rs = rsqrtf(ss * (1.f / 512.f) - m * m + LN_EPS);
    float4 ga = *(const float4*)&g[cb];
    float4 gb = *(const float4*)&g[cb + 4];
    float4 ea = *(const float4*)&be[cb];
    float4 eb = *(const float4*)&be[cb + 4];
    float gg[8] = {ga.x, ga.y, ga.z, ga.w, gb.x, gb.y, gb.z, gb.w};
    float ee[8] = {ea.x, ea.y, ea.z, ea.w, eb.x, eb.y, eb.z, eb.w};
    float z[8];
#pragma unroll
    for (int j = 0; j < 8; ++j) {
        float zz = gg[j] * (v[j] - m) * rs + ee[j];
        z[j] = (zz > 0.f) ? zz : NEG_SLOPE * zz;
    }
    if (zb) {
        ushort4 o0, o1;
        o0.x = f2bf(z[0]); o0.y = f2bf(z[1]); o0.z = f2bf(z[2]); o0.w = f2bf(z[3]);
        o1.x = f2bf(z[4]); o1.y = f2bf(z[5]); o1.z = f2bf(z[6]); o1.w = f2bf(z[7]);
        *(ushort4*)&zb[base] = o0;
        *(ushort4*)&zb[base + 4] = o1;
    }
    if (hbf) {
        float4 ra = *(const float4*)&res[base];
        float4 rb2 = *(const float4*)&res[base + 4];
        ushort4 o0, o1;
        o0.x = f2bf(ra.x + z[0]); o0.y = f2bf(ra.y + z[1]);
        o0.z = f2bf(ra.z + z[2]); o0.w = f2bf(ra.w + z[3]);
        o1.x = f2bf(rb2.x + z[4]); o1.y = f2bf(rb2.y + z[5]);
        o1.z = f2bf(rb2.z + z[6]); o1.w = f2bf(rb2.w + z[7]);
        *(ushort4*)&hbf[base] = o0;
        *(ushort4*)&hbf[base + 4] = o1;
    }
    if (fout) {
        *(float4*)&fout[base] = make_float4(z[0], z[1], z[2], z[3]);
        *(float4*)&fout[base + 4] = make_float4(z[4], z[5], z[6], z[7]);
    }
}

// ---------------------------------------------------------------------------
extern "C" void kernel_launch(void* const* d_in, const int* in_sizes, int n_in,
                              void* d_out, int out_size, void* d_ws, size_t ws_size,
                              hipStream_t stream) {
    const float* x     = (const float*)d_in[0];
    const int*   start = (const int*)d_in[1];
    const float* s0r = (const float*)d_in[3];
    const float* s0i = (const float*)d_in[4];
    const float* Wt  = (const float*)d_in[5];
    const float* Wc  = (const float*)d_in[6];
    const float* a   = (const float*)d_in[7];
    const float* b   = (const float*)d_in[8];
    const float* W0  = (const float*)d_in[9];
    const float* b0  = (const float*)d_in[10];
    const float* g0  = (const float*)d_in[11];
    const float* be0 = (const float*)d_in[12];
    const float* W1  = (const float*)d_in[13];
    const float* b1  = (const float*)d_in[14];
    const float* g1  = (const float*)d_in[15];
    const float* be1 = (const float*)d_in[16];
    float* out = (float*)d_out;
    float* ws  = (float*)d_ws;

    // workspace layout (float-unit offsets, all 16B aligned)
    float* p = ws;
    float* tcabs  = p; p += 262144;                  // [4096][64] f32 (invd folded)
    float4* ab4   = (float4*)p; p += 524288;         // [128][1024] float4
    unsigned short* scaled = (unsigned short*)p; p += 4194304;   // [4096][2048] bf16
    unsigned short* ybufp_bf = (unsigned short*)p; p += 2097152; // [2][4096][512] bf16 partials
    unsigned short* zbuf_bf = (unsigned short*)p; p += 1048576;  // [4096][512] bf16
    unsigned short* x_bf    = (unsigned short*)p; p += 1048576;
    unsigned short* h_bf    = (unsigned short*)p; p += 1048576;
    unsigned short* Wtcbf   = (unsigned short*)p; p += 32768;    // [2][64][512] bf16
    unsigned short* W0bf    = (unsigned short*)p; p += 1048576;  // [2][512][2048] bf16
    unsigned short* W1bf    = (unsigned short*)p; p += 262144;   // [2][512][512] bf16
    float2* ggt = (float2*)p; p += 4096;             // [2][1024] float2

    setup_kernel<<<(NCV + NPK + NGG + 255) / 256, 256, 0, stream>>>(
        (const float4*)x, (const float4*)W0, (const float4*)W1, Wt, Wc, a, b,
        (ushort4*)x_bf, (ushort4*)W0bf, (ushort4*)W1bf, (ushort4*)Wtcbf, ggt);

    for (int i = 0; i < LL; ++i) {
        const unsigned short* hb = (i == 0) ? x_bf : h_bf;
        proj_denom_kernel<<<64, 256, 0, stream>>>(
            hb, Wtcbf + (size_t)i * 64 * 512, tcabs);
        {
            const float* tc_c = tcabs;
            float4* ab4_c = ab4;
            const int* start_c = start;
            const float2* ggt_c = ggt + (size_t)i * RC;
            const float* s0r_c = s0r + (size_t)i * RC;
            const float* s0i_c = s0i + (size_t)i * RC;
            unsigned short* scaled_c = scaled;
            void* kargs[] = {(void*)&tc_c, (void*)&ab4_c, (void*)&start_c,
                             (void*)&ggt_c, (void*)&s0r_c, (void*)&s0i_c,
                             (void*)&scaled_c};
            hipLaunchCooperativeKernel((const void*)scan_fused, dim3(512), dim3(256),
                                       kargs, 0, stream);
        }
        gemm_bt_mfma<2048, 512, 2><<<dim3(8, 32, 2), 256, 0, stream>>>(
            scaled, W0bf + (size_t)i * 512 * 2048, ybufp_bf);
        ln_lrelu_kernel<2><<<1024, 256, 0, stream>>>(
            ybufp_bf, b0 + i * DD, g0 + i * DD, be0 + i * DD,
            zbuf_bf, nullptr, nullptr, nullptr);
        gemm_bt_mfma<512, 512, 2><<<dim3(8, 32, 2), 256, 0, stream>>>(
            zbuf_bf, W1bf + (size_t)i * 512 * 512, ybufp_bf);
        ln_lrelu_kernel<2><<<1024, 256, 0, stream>>>(
            ybufp_bf, b1 + i * DD, g1 + i * DD, be1 + i * DD,
            nullptr,
            (i < LL - 1) ? x : nullptr,
            (i < LL - 1) ? h_bf : nullptr,
            (i == LL - 1) ? out : nullptr);
    }
}

// Round 17
// 176.786 us; speedup vs baseline: 1.9699x; 1.9699x over previous
//
#include <hip/hip_runtime.h>
#include <math.h>

// Problem constants
#define TT 4096
#define DD 512
#define RR 32
#define CC 32
#define RC 1024
#define LL 2
#define CHUNK 32
#define NCHUNK 128
#define NEG_SLOPE 0.01f
#define LN_EPS 1e-5f

typedef __attribute__((ext_vector_type(8))) __bf16 bf16x8;
typedef __attribute__((ext_vector_type(4))) float f32x4;

__device__ __forceinline__ unsigned short f2bf(float f) {
    unsigned int u = __builtin_bit_cast(unsigned int, f);
    u += 0x7fffu + ((u >> 16) & 1u);   // round-to-nearest-even
    return (unsigned short)(u >> 16);
}
__device__ __forceinline__ float bf2f(unsigned short s) {
    unsigned int u = (unsigned int)s << 16;
    return __builtin_bit_cast(float, u);
}

// ---------------------------------------------------------------------------
// Fused setup: f32->bf16 for x, W0, W1; Wt/Wc pack into Wtc[L,64,512];
// gamma table ggt[L][1024] = e^{-|a_r|} * (cos b_c, sin b_c).
#define NX4  524288   // 4096*512/4
#define NW04 524288   // 2*512*2048/4
#define NW14 131072   // 2*512*512/4
#define NCV  (NX4 + NW04 + NW14)
#define NPK  16384    // 2*64*512/4
#define NGG  2048     // 2*1024
__global__ __launch_bounds__(256) void setup_kernel(const float4* __restrict__ x,
                                                    const float4* __restrict__ W0,
                                                    const float4* __restrict__ W1,
                                                    const float* __restrict__ Wt,
                                                    const float* __restrict__ Wc,
                                                    const float* __restrict__ a,
                                                    const float* __restrict__ b,
                                                    ushort4* __restrict__ xb,
                                                    ushort4* __restrict__ W0b,
                                                    ushort4* __restrict__ W1b,
                                                    ushort4* __restrict__ Wtc,
                                                    float2* __restrict__ ggt) {
    int i = blockIdx.x * 256 + threadIdx.x;
    float4 v;
    ushort4* dst;
    int j;
    if (i < NCV) {
        const float4* src;
        if (i < NX4) { src = x; dst = xb; j = i; }
        else if (i < NX4 + NW04) { src = W0; dst = W0b; j = i - NX4; }
        else { src = W1; dst = W1b; j = i - NX4 - NW04; }
        v = src[j];
    } else {
        int ii = i - NCV;
        if (ii < NPK) {
            int e = ii * 4;
            int l = e >> 15;
            int r = (e >> 9) & 63;
            int k = e & 511;
            v = (r < 32) ? *(const float4*)&Wt[((size_t)l * 32 + r) * 512 + k]
                         : *(const float4*)&Wc[((size_t)l * 32 + (r - 32)) * 512 + k];
            dst = Wtc; j = ii;
        } else {
            int ii2 = ii - NPK;
            if (ii2 >= NGG) return;
            int l = ii2 >> 10;
            int rc = ii2 & 1023;
            int r = rc >> 5, c = rc & 31;
            float e = expf(-fabsf(a[l * RR + r]));
            ggt[ii2] = make_float2(e * cosf(b[l * CC + c]), e * sinf(b[l * CC + c]));
            return;
        }
    }
    ushort4 o;
    o.x = f2bf(v.x); o.y = f2bf(v.y); o.z = f2bf(v.z); o.w = f2bf(v.w);
    dst[j] = o;
}

// ---------------------------------------------------------------------------
// proj + denom fused (R14 champion): tcabs[t,r]=|tr_r|*invd; tcabs[t,32+c]=|ct_c|.
// Tile 64x64, BK=64, 4 waves; named-scalar staging; grid 64.
__global__ __launch_bounds__(256) void proj_denom_kernel(const unsigned short* __restrict__ A,
                                                         const unsigned short* __restrict__ B,
                                                         float* __restrict__ tcabs) {
    __shared__ __align__(16) unsigned short As[64 * 64];
    __shared__ __align__(16) unsigned short Bs[64 * 64];
    const int tid = threadIdx.x;
    const int w = tid >> 6, lane = tid & 63;
    const int bm = blockIdx.x * 64;
    const int K = 512;
    const int srow = tid >> 3;               // 0..31
    const int k8 = tid & 7;
    const int swz = (k8 ^ (srow & 7)) * 8;
    const unsigned short* gA = A + (size_t)(bm + srow) * K + k8 * 8;
    const unsigned short* gB = B + (size_t)srow * K + k8 * 8;
    const int wb = srow * 64 + swz;
    const int fr = lane & 15, hi = lane >> 4;
    f32x4 acc0 = {}, acc1 = {}, acc2 = {}, acc3 = {};

    uint4 va0 = *(const uint4*)gA;
    uint4 va1 = *(const uint4*)(gA + (size_t)32 * K);
    uint4 vb0 = *(const uint4*)gB;
    uint4 vb1 = *(const uint4*)(gB + (size_t)32 * K);
    for (int k0 = 0; k0 < K; k0 += 64) {
        __syncthreads();
        *(uint4*)&As[wb]        = va0;
        *(uint4*)&As[wb + 2048] = va1;
        *(uint4*)&Bs[wb]        = vb0;
        *(uint4*)&Bs[wb + 2048] = vb1;
        __syncthreads();
        if (k0 + 64 < K) {
            va0 = *(const uint4*)(gA + k0 + 64);
            va1 = *(const uint4*)(gA + (size_t)32 * K + k0 + 64);
            vb0 = *(const uint4*)(gB + k0 + 64);
            vb1 = *(const uint4*)(gB + (size_t)32 * K + k0 + 64);
        }
        const int arow = w * 16 + fr;
#pragma unroll
        for (int kk = 0; kk < 2; ++kk) {
            const int ks = kk * 4 + hi;      // 0..7
            bf16x8 af = *(const bf16x8*)&As[arow * 64 + ((ks ^ (arow & 7)) * 8)];
            bf16x8 b0 = *(const bf16x8*)&Bs[(0 * 16 + fr) * 64 + ((ks ^ (fr & 7)) * 8)];
            bf16x8 b1 = *(const bf16x8*)&Bs[(1 * 16 + fr) * 64 + ((ks ^ (fr & 7)) * 8)];
            bf16x8 b2 = *(const bf16x8*)&Bs[(2 * 16 + fr) * 64 + ((ks ^ (fr & 7)) * 8)];
            bf16x8 b3 = *(const bf16x8*)&Bs[(3 * 16 + fr) * 64 + ((ks ^ (fr & 7)) * 8)];
            acc0 = __builtin_amdgcn_mfma_f32_16x16x32_bf16(af, b0, acc0, 0, 0, 0);
            acc1 = __builtin_amdgcn_mfma_f32_16x16x32_bf16(af, b1, acc1, 0, 0, 0);
            acc2 = __builtin_amdgcn_mfma_f32_16x16x32_bf16(af, b2, acc2, 0, 0, 0);
            acc3 = __builtin_amdgcn_mfma_f32_16x16x32_bf16(af, b3, acc3, 0, 0, 0);
        }
    }
#pragma unroll
    for (int q = 0; q < 4; ++q) {
        float a0 = fabsf(acc0[q]), a1 = fabsf(acc1[q]);
        float a2 = fabsf(acc2[q]), a3 = fabsf(acc3[q]);
        float st = a0 + a1, sc = a2 + a3;
        st += __shfl_xor(st, 1); sc += __shfl_xor(sc, 1);
        st += __shfl_xor(st, 2); sc += __shfl_xor(sc, 2);
        st += __shfl_xor(st, 4); sc += __shfl_xor(sc, 4);
        st += __shfl_xor(st, 8); sc += __shfl_xor(sc, 8);
        float inv = 1.f / (1e-8f + st * sc);
        size_t rb = (size_t)(bm + w * 16 + hi * 4 + q) * 64;
        tcabs[rb + fr]      = a0 * inv;
        tcabs[rb + fr + 16] = a1 * inv;
        tcabs[rb + fr + 32] = a2;
        tcabs[rb + fr + 48] = a3;
    }
}

// ---------------------------------------------------------------------------
// Scan pass 1: per (chunk, r, c) affine transform (alpha, beta) with resets.
__global__ __launch_bounds__(256) void scan_pass1(const float* __restrict__ tcabs,
                                                  const int* __restrict__ start,
                                                  const float2* __restrict__ ggt,
                                                  float4* __restrict__ ab4) {
    int tid = blockIdx.x * 256 + threadIdx.x;   // NCHUNK*RC = 131072
    int rc = tid & (RC - 1);
    int chunk = tid >> 10;
    int r = rc >> 5, c = rc & 31;
    float2 gg = ggt[rc];
    float gr = gg.x, gi = gg.y;
    float alr = 1.f, ali = 0.f, ber = 0.f, bei = 0.f;
    int t0 = chunk * CHUNK;
    for (int j = 0; j < CHUNK; ++j) {
        int t = t0 + j;
        float pre = tcabs[t * 64 + r] * tcabs[t * 64 + 32 + c];
        if (start[t]) {
            alr = 0.f; ali = 0.f; ber = pre; bei = 0.f;
        } else {
            float nbr = pre + gr * ber - gi * bei;
            float nbi =       gr * bei + gi * ber;
            float nar = gr * alr - gi * ali;
            float nai = gr * ali + gi * alr;
            ber = nbr; bei = nbi; alr = nar; ali = nai;
        }
    }
    ab4[chunk * RC + rc] = make_float4(alr, ali, ber, bei);
}

// ---------------------------------------------------------------------------
// Scan pass 2 + in-block lookback: compose ab4[0..chunk-1] (8-deep prefetch),
// then rescan own chunk, emit scaled features (bf16).
// grid 512; cid = bx>>2 remapped light/heavy-interleaved for load balance.
__global__ __launch_bounds__(256) void scan_pass2f(const float* __restrict__ tcabs,
                                                   const float4* __restrict__ ab4,
                                                   const int* __restrict__ start,
                                                   const float2* __restrict__ ggt,
                                                   const float* __restrict__ s0r,
                                                   const float* __restrict__ s0i,
                                                   unsigned short* __restrict__ scaled) {
    int bx = blockIdx.x;
    int cid = bx >> 2;
    int chunk = (cid & 1) ? (NCHUNK - 1 - (cid >> 1)) : (cid >> 1);
    int rc = (bx & 3) * 256 + threadIdx.x;
    int r = rc >> 5, c = rc & 31;
    float2 gg = ggt[rc];
    float gr = gg.x, gi = gg.y;
    float sr = s0r[rc], si = s0i[rc];
    int j = 0;
    for (; j + 8 <= chunk; j += 8) {
        float4 buf[8];
#pragma unroll
        for (int u = 0; u < 8; ++u) buf[u] = ab4[(j + u) * RC + rc];
#pragma unroll
        for (int u = 0; u < 8; ++u) {
            float nsr = buf[u].z + buf[u].x * sr - buf[u].y * si;
            float nsi = buf[u].w + buf[u].x * si + buf[u].y * sr;
            sr = nsr; si = nsi;
        }
    }
    for (; j < chunk; ++j) {
        float4 ab = ab4[j * RC + rc];
        float nsr = ab.z + ab.x * sr - ab.y * si;
        float nsi = ab.w + ab.x * si + ab.y * sr;
        sr = nsr; si = nsi;
    }
    int t0 = chunk * CHUNK;
    for (int jj = 0; jj < CHUNK; ++jj) {
        int t = t0 + jj;
        float pre = tcabs[t * 64 + r] * tcabs[t * 64 + 32 + c];
        if (start[t]) {
            sr = pre; si = 0.f;
        } else {
            float nsr = pre + gr * sr - gi * si;
            float nsi =       gr * si + gi * sr;
            sr = nsr; si = nsi;
        }
        float m2 = sr * sr + si * si;
        float rsq = rsqrtf(m2);
        float m = m2 * rsq;                    // |s|
        float f = (m2 > 0.f) ? log1pf(m) * rsq : 0.f;   // log1p(|s|)/|s|
        scaled[(size_t)t * 2048 + rc]        = f2bf(si * f);
        scaled[(size_t)t * 2048 + 1024 + rc] = f2bf(sr * f);
    }
}

// ---------------------------------------------------------------------------
// Cm_partial[z][4096,N] = A[4096,Kz]bf16 @ B[N,Kz]bf16^T, stored as BF16
// (LN re-sums in fp32). Tile 128x64, BK=64, 4 waves, named-scalar staging
// (R13/R14 champion). XCD-chunked block swizzle (bijective, nwg % 8 == 0).
template <int K, int N, int SPLITK>
__global__ __launch_bounds__(256) void gemm_bt_mfma(const unsigned short* __restrict__ A,
                                                    const unsigned short* __restrict__ B,
                                                    unsigned short* __restrict__ Cm) {
    __shared__ __align__(16) unsigned short As[128 * 64];
    __shared__ __align__(16) unsigned short Bs[64 * 64];
    const int tid = threadIdx.x;
    const int w = tid >> 6, lane = tid & 63;
    const int nwg = gridDim.x * gridDim.y * gridDim.z;
    const int id = blockIdx.x + gridDim.x * (blockIdx.y + gridDim.y * blockIdx.z);
    const int lid = (id & 7) * (nwg >> 3) + (id >> 3);
    const int bxs = lid % gridDim.x;
    const int t2 = lid / gridDim.x;
    const int bys = t2 % gridDim.y;
    const int bzs = t2 / gridDim.y;
    const int bm = bys * 128, bn = bxs * 64;
    const int kbeg = bzs * (K / SPLITK);
    const int kend = kbeg + (K / SPLITK);
    const int wr = w >> 1, wc = w & 1;
    const int srow = tid >> 3;               // 0..31
    const int k8 = tid & 7;
    const int swz = (k8 ^ (srow & 7)) * 8;
    const unsigned short* gA = A + (size_t)(bm + srow) * K + k8 * 8;
    const unsigned short* gB = B + (size_t)(bn + srow) * K + k8 * 8;
    const int wAb = srow * 64 + swz;
    const int fr = lane & 15, hi = lane >> 4;
    f32x4 acc[4][2] = {};

    uint4 va0 = *(const uint4*)(gA + kbeg);
    uint4 va1 = *(const uint4*)(gA + (size_t)32 * K + kbeg);
    uint4 va2 = *(const uint4*)(gA + (size_t)64 * K + kbeg);
    uint4 va3 = *(const uint4*)(gA + (size_t)96 * K + kbeg);
    uint4 vb0 = *(const uint4*)(gB + kbeg);
    uint4 vb1 = *(const uint4*)(gB + (size_t)32 * K + kbeg);
    for (int k0 = kbeg; k0 < kend; k0 += 64) {
        __syncthreads();
        *(uint4*)&As[wAb]        = va0;
        *(uint4*)&As[wAb + 2048] = va1;
        *(uint4*)&As[wAb + 4096] = va2;
        *(uint4*)&As[wAb + 6144] = va3;
        *(uint4*)&Bs[wAb]        = vb0;
        *(uint4*)&Bs[wAb + 2048] = vb1;
        __syncthreads();
        if (k0 + 64 < kend) {
            va0 = *(const uint4*)(gA + k0 + 64);
            va1 = *(const uint4*)(gA + (size_t)32 * K + k0 + 64);
            va2 = *(const uint4*)(gA + (size_t)64 * K + k0 + 64);
            va3 = *(const uint4*)(gA + (size_t)96 * K + k0 + 64);
            vb0 = *(const uint4*)(gB + k0 + 64);
            vb1 = *(const uint4*)(gB + (size_t)32 * K + k0 + 64);
        }
#pragma unroll
        for (int kk = 0; kk < 2; ++kk) {
            const int ks = kk * 4 + hi;      // 0..7
            bf16x8 af[4], bfv[2];
#pragma unroll
            for (int mi = 0; mi < 4; ++mi) {
                int row = wr * 64 + mi * 16 + fr;
                af[mi] = *(const bf16x8*)&As[row * 64 + ((ks ^ (row & 7)) * 8)];
            }
#pragma unroll
            for (int ni = 0; ni < 2; ++ni) {
                int row = wc * 32 + ni * 16 + fr;
                bfv[ni] = *(const bf16x8*)&Bs[row * 64 + ((ks ^ (row & 7)) * 8)];
            }
#pragma unroll
            for (int mi = 0; mi < 4; ++mi)
#pragma unroll
                for (int ni = 0; ni < 2; ++ni)
                    acc[mi][ni] = __builtin_amdgcn_mfma_f32_16x16x32_bf16(
                        af[mi], bfv[ni], acc[mi][ni], 0, 0, 0);
        }
    }
    // epilogue: C/D layout col=lane&15, row=(lane>>4)*4+reg  [m89]
    unsigned short* Cz = Cm + (size_t)bzs * TT * N;
    const int ccol0 = bn + wc * 32 + fr;
    const int crow0 = bm + wr * 64 + hi * 4;
#pragma unroll
    for (int ni = 0; ni < 2; ++ni) {
        int col = ccol0 + ni * 16;
#pragma unroll
        for (int mi = 0; mi < 4; ++mi)
#pragma unroll
            for (int q = 0; q < 4; ++q)
                Cz[(size_t)(crow0 + mi * 16 + q) * N + col] = f2bf(acc[mi][ni][q]);
    }
}

// ---------------------------------------------------------------------------
// Wave-per-row LayerNorm + LeakyReLU: y = y0 + y1 + bias (bf16 partials).
// grid 1024 x 256 thr; wave owns one row, lane covers 8 cols.
__global__ __launch_bounds__(256) void ln_lrelu_kernel(const unsigned short* __restrict__ y0,
                                                       const unsigned short* __restrict__ y1,
                                                       const float* __restrict__ badd,
                                                       const float* __restrict__ g,
                                                       const float* __restrict__ be,
                                                       unsigned short* __restrict__ zb,
                                                       const float* __restrict__ res,
                                                       unsigned short* __restrict__ hbf,
                                                       float* __restrict__ fout) {
    const int lane = threadIdx.x & 63;
    const int row = blockIdx.x * 4 + (threadIdx.x >> 6);
    const size_t base = (size_t)row * 512 + lane * 8;
    const int cb = lane * 8;
    ushort4 ua0 = *(const ushort4*)&y0[base];
    ushort4 ua1 = *(const ushort4*)&y0[base + 4];
    ushort4 ub0 = *(const ushort4*)&y1[base];
    ushort4 ub1 = *(const ushort4*)&y1[base + 4];
    float4 ba = *(const float4*)&badd[cb];
    float4 bb = *(const float4*)&badd[cb + 4];
    float v[8];
    v[0] = bf2f(ua0.x) + bf2f(ub0.x) + ba.x;
    v[1] = bf2f(ua0.y) + bf2f(ub0.y) + ba.y;
    v[2] = bf2f(ua0.z) + bf2f(ub0.z) + ba.z;
    v[3] = bf2f(ua0.w) + bf2f(ub0.w) + ba.w;
    v[4] = bf2f(ua1.x) + bf2f(ub1.x) + bb.x;
    v[5] = bf2f(ua1.y) + bf2f(ub1.y) + bb.y;
    v[6] = bf2f(ua1.z) + bf2f(ub1.z) + bb.z;
    v[7] = bf2f(ua1.w) + bf2f(ub1.w) + bb.w;
    float s = 0.f, ss = 0.f;
#pragma unroll
    for (int j = 0; j < 8; ++j) { s += v[j]; ss += v[j] * v[j]; }
#pragma unroll
    for (int o = 1; o < 64; o <<= 1) {
        s  += __shfl_xor(s, o);
        ss += __shfl_xor(ss, o);
    }
    float m = s * (1.f / 512.f);
    float rs = rsqrtf(ss * (1.f / 512.f) - m * m + LN_EPS);
    float4 ga = *(const float4*)&g[cb];
    float4 gb = *(const float4*)&g[cb + 4];
    float4 ea = *(const float4*)&be[cb];
    float4 eb = *(const float4*)&be[cb + 4];
    float gg[8] = {ga.x, ga.y, ga.z, ga.w, gb.x, gb.y, gb.z, gb.w};
    float ee[8] = {ea.x, ea.y, ea.z, ea.w, eb.x, eb.y, eb.z, eb.w};
    float z[8];
#pragma unroll
    for (int j = 0; j < 8; ++j) {
        float zz = gg[j] * (v[j] - m) * rs + ee[j];
        z[j] = (zz > 0.f) ? zz : NEG_SLOPE * zz;
    }
    if (zb) {
        ushort4 o0, o1;
        o0.x = f2bf(z[0]); o0.y = f2bf(z[1]); o0.z = f2bf(z[2]); o0.w = f2bf(z[3]);
        o1.x = f2bf(z[4]); o1.y = f2bf(z[5]); o1.z = f2bf(z[6]); o1.w = f2bf(z[7]);
        *(ushort4*)&zb[base] = o0;
        *(ushort4*)&zb[base + 4] = o1;
    }
    if (hbf) {
        float4 ra = *(const float4*)&res[base];
        float4 rb2 = *(const float4*)&res[base + 4];
        ushort4 o0, o1;
        o0.x = f2bf(ra.x + z[0]); o0.y = f2bf(ra.y + z[1]);
        o0.z = f2bf(ra.z + z[2]); o0.w = f2bf(ra.w + z[3]);
        o1.x = f2bf(rb2.x + z[4]); o1.y = f2bf(rb2.y + z[5]);
        o1.z = f2bf(rb2.z + z[6]); o1.w = f2bf(rb2.w + z[7]);
        *(ushort4*)&hbf[base] = o0;
        *(ushort4*)&hbf[base + 4] = o1;
    }
    if (fout) {
        *(float4*)&fout[base] = make_float4(z[0], z[1], z[2], z[3]);
        *(float4*)&fout[base + 4] = make_float4(z[4], z[5], z[6], z[7]);
    }
}

// ---------------------------------------------------------------------------
extern "C" void kernel_launch(void* const* d_in, const int* in_sizes, int n_in,
                              void* d_out, int out_size, void* d_ws, size_t ws_size,
                              hipStream_t stream) {
    const float* x     = (const float*)d_in[0];
    const int*   start = (const int*)d_in[1];
    const float* s0r = (const float*)d_in[3];
    const float* s0i = (const float*)d_in[4];
    const float* Wt  = (const float*)d_in[5];
    const float* Wc  = (const float*)d_in[6];
    const float* a   = (const float*)d_in[7];
    const float* b   = (const float*)d_in[8];
    const float* W0  = (const float*)d_in[9];
    const float* b0  = (const float*)d_in[10];
    const float* g0  = (const float*)d_in[11];
    const float* be0 = (const float*)d_in[12];
    const float* W1  = (const float*)d_in[13];
    const float* b1  = (const float*)d_in[14];
    const float* g1  = (const float*)d_in[15];
    const float* be1 = (const float*)d_in[16];
    float* out = (float*)d_out;
    float* ws  = (float*)d_ws;

    // workspace layout (float-unit offsets, all 16B aligned)  ~44 MB
    float* p = ws;
    float* tcabs  = p; p += 262144;                  // [4096][64] f32 (invd folded)
    float4* ab4   = (float4*)p; p += 524288;         // [128][1024] float4
    unsigned short* scaled = (unsigned short*)p; p += 4194304;   // [4096][2048] bf16
    unsigned short* ybufp_bf = (unsigned short*)p; p += 2097152; // [2][4096][512] bf16 partials
    unsigned short* zbuf_bf = (unsigned short*)p; p += 1048576;  // [4096][512] bf16
    unsigned short* x_bf    = (unsigned short*)p; p += 1048576;
    unsigned short* h_bf    = (unsigned short*)p; p += 1048576;
    unsigned short* Wtcbf   = (unsigned short*)p; p += 32768;    // [2][64][512] bf16
    unsigned short* W0bf    = (unsigned short*)p; p += 1048576;  // [2][512][2048] bf16
    unsigned short* W1bf    = (unsigned short*)p; p += 262144;   // [2][512][512] bf16
    float2* ggt = (float2*)p; p += 4096;             // [2][1024] float2

    setup_kernel<<<(NCV + NPK + NGG + 255) / 256, 256, 0, stream>>>(
        (const float4*)x, (const float4*)W0, (const float4*)W1, Wt, Wc, a, b,
        (ushort4*)x_bf, (ushort4*)W0bf, (ushort4*)W1bf, (ushort4*)Wtcbf, ggt);

    for (int i = 0; i < LL; ++i) {
        const unsigned short* hb = (i == 0) ? x_bf : h_bf;
        proj_denom_kernel<<<64, 256, 0, stream>>>(
            hb, Wtcbf + (size_t)i * 64 * 512, tcabs);
        scan_pass1<<<NCHUNK * RC / 256, 256, 0, stream>>>(
            tcabs, start, ggt + (size_t)i * RC, ab4);
        scan_pass2f<<<NCHUNK * 4, 256, 0, stream>>>(
            tcabs, ab4, start, ggt + (size_t)i * RC,
            s0r + i * RC, s0i + i * RC, scaled);
        gemm_bt_mfma<2048, 512, 2><<<dim3(8, 32, 2), 256, 0, stream>>>(
            scaled, W0bf + (size_t)i * 512 * 2048, ybufp_bf);
        ln_lrelu_kernel<<<1024, 256, 0, stream>>>(
            ybufp_bf, ybufp_bf + (size_t)TT * 512, b0 + i * DD, g0 + i * DD, be0 + i * DD,
            zbuf_bf, nullptr, nullptr, nullptr);
        gemm_bt_mfma<512, 512, 2><<<dim3(8, 32, 2), 256, 0, stream>>>(
            zbuf_bf, W1bf + (size_t)i * 512 * 512, ybufp_bf);
        ln_lrelu_kernel<<<1024, 256, 0, stream>>>(
            ybufp_bf, ybufp_bf + (size_t)TT * 512, b1 + i * DD, g1 + i * DD, be1 + i * DD,
            nullptr,
            (i < LL - 1) ? x : nullptr,
            (i < LL - 1) ? h_bf : nullptr,
            (i == LL - 1) ? out : nullptr);
    }
}